// Round 1
// baseline (454.724 us; speedup 1.0000x reference)
//
#include <hip/hip_runtime.h>
#include <hip/hip_bf16.h>

using bf16 = __hip_bfloat16;
typedef short s16x8 __attribute__((ext_vector_type(8)));
typedef float f32x4 __attribute__((ext_vector_type(4)));
typedef unsigned short u16;

// ---------- helpers ----------
__device__ __forceinline__ void gld_lds16(const void* g, void* l) {
  __builtin_amdgcn_global_load_lds(
      (const __attribute__((address_space(1))) void*)g,
      (__attribute__((address_space(3))) void*)l, 16, 0, 0);
}

__device__ __forceinline__ float bf2f(u16 u) {
  unsigned int x = ((unsigned int)u) << 16;
  return __builtin_bit_cast(float, x);
}
__device__ __forceinline__ u16 f2bf(float f) {
  return __builtin_bit_cast(u16, __float2bfloat16(f));
}

// ---------- fp32 -> bf16 elementwise convert ----------
__global__ __launch_bounds__(256) void convert_f32_bf16(
    const float* __restrict__ in, bf16* __restrict__ out, int n) {
  int i = blockIdx.x * 256 + threadIdx.x;
  if (i < n) out[i] = __float2bfloat16(in[i]);
}

// ---------- transpose [C][inner] fp32 -> [inner][out_ld] bf16 (out[p][c] = in[c][p]) ----------
__global__ __launch_bounds__(256) void transpose_f32_to_bf16(
    const float* __restrict__ in, bf16* __restrict__ out, int inner,
    long in_b, long out_b, int out_ld, int coloff) {
  __shared__ float tile[32][33];
  const int bx = blockIdx.x;  // inner tile
  const int by = blockIdx.y;  // outer tile
  const int bz = blockIdx.z;
  const int tx = threadIdx.x & 31;
  const int ty = threadIdx.x >> 5;  // 0..7
  const float* ib = in + (long)bz * in_b;
  bf16* ob = out + (long)bz * out_b;
#pragma unroll
  for (int i = 0; i < 4; ++i) {
    int r = ty + i * 8;
    tile[r][tx] = ib[(long)(by * 32 + r) * inner + bx * 32 + tx];
  }
  __syncthreads();
#pragma unroll
  for (int i = 0; i < 4; ++i) {
    int r = ty + i * 8;
    ob[(long)(bx * 32 + r) * out_ld + coloff + by * 32 + tx] =
        __float2bfloat16(tile[tx][r]);
  }
}

// ---------- GEMM: C[M,N] = alpha * A[M,K] @ B[N,K]^T (+bias) ----------
// A bf16 row-major lda, B bf16 row-major ldb (i.e. B^T layout), C row-major ldc.
// BIAS_MODE: 0 none, 1 per-col (bias[n]), 2 per-row (bias[m]).
// 128x128 tile, BK=64, 256 threads = 4 waves in 2x2, mfma 16x16x32 bf16.
template <int OUT_BF16, int BIAS_MODE>
__global__ __launch_bounds__(256, 2) void gemm_bt_kernel(
    const bf16* __restrict__ A, long sAb, int lda,
    const bf16* __restrict__ B, long sBb, int ldb,
    void* __restrict__ Cp, long sCb, int ldc,
    const float* __restrict__ bias, float alpha, int K) {
  __shared__ __align__(16) bf16 tA[128 * 64];
  __shared__ __align__(16) bf16 tB[128 * 64];

  const int t = threadIdx.x;
  const int w = t >> 6;
  const int lane = t & 63;
  const int bn = blockIdx.x;
  const int bm = blockIdx.y;
  const int bz = blockIdx.z;

  const bf16* Ab = A + (long)bz * sAb;
  const bf16* Bb = B + (long)bz * sBb;

  const int srow = t >> 3;         // 0..31
  const int scol = (t & 7) * 8;    // element col within BK
  const long a_base = (long)(bm * 128 + srow) * lda + scol;
  const long b_base = (long)(bn * 128 + srow) * ldb + scol;
  char* lA = (char*)tA + w * 1024;  // wave-uniform LDS base; HW adds lane*16
  char* lB = (char*)tB + w * 1024;

  const int wr = w >> 1, wc = w & 1;
  f32x4 acc[4][4] = {};

  for (int kt = 0; kt < K; kt += 64) {
#pragma unroll
    for (int i = 0; i < 4; ++i) {
      gld_lds16(Ab + a_base + (long)(i * 32) * lda + kt, lA + i * 4096);
      gld_lds16(Bb + b_base + (long)(i * 32) * ldb + kt, lB + i * 4096);
    }
    __syncthreads();
#pragma unroll
    for (int kk = 0; kk < 2; ++kk) {
      const int krd = kk * 32 + (lane >> 4) * 8;
      s16x8 af[4], bg[4];
#pragma unroll
      for (int m = 0; m < 4; ++m)
        af[m] = *(const s16x8*)(tA + (wr * 64 + m * 16 + (lane & 15)) * 64 + krd);
#pragma unroll
      for (int n = 0; n < 4; ++n)
        bg[n] = *(const s16x8*)(tB + (wc * 64 + n * 16 + (lane & 15)) * 64 + krd);
#pragma unroll
      for (int m = 0; m < 4; ++m)
#pragma unroll
        for (int n = 0; n < 4; ++n)
          acc[m][n] = __builtin_amdgcn_mfma_f32_16x16x32_bf16(af[m], bg[n],
                                                              acc[m][n], 0, 0, 0);
    }
    __syncthreads();
  }

  // epilogue: C/D layout col = lane&15, row = (lane>>4)*4 + j  [m89-verified]
#pragma unroll
  for (int m = 0; m < 4; ++m) {
    const int rb = bm * 128 + wr * 64 + m * 16 + (lane >> 4) * 4;
#pragma unroll
    for (int n = 0; n < 4; ++n) {
      const int col = bn * 128 + wc * 64 + n * 16 + (lane & 15);
      float bN = 0.f;
      if (BIAS_MODE == 1) bN = bias[col];
#pragma unroll
      for (int j = 0; j < 4; ++j) {
        const int row = rb + j;
        float v = acc[m][n][j] * alpha;
        if (BIAS_MODE == 1) v += bN;
        if (BIAS_MODE == 2) v += bias[row];
        const long off = (long)bz * sCb + (long)row * ldc + col;
        if (OUT_BF16)
          ((bf16*)Cp)[off] = __float2bfloat16(v);
        else
          ((float*)Cp)[off] = v;
      }
    }
  }
}

// ---------- row softmax over 1024 bf16, in place ----------
__global__ __launch_bounds__(256) void softmax_rows_1024(u16* __restrict__ S) {
  const long row = blockIdx.x;
  u16* p = S + row * 1024;
  const int t = threadIdx.x;
  ushort4 raw = *(const ushort4*)(p + t * 4);
  float v0 = bf2f(raw.x), v1 = bf2f(raw.y), v2 = bf2f(raw.z), v3 = bf2f(raw.w);
  float m = fmaxf(fmaxf(v0, v1), fmaxf(v2, v3));
#pragma unroll
  for (int s = 32; s > 0; s >>= 1) m = fmaxf(m, __shfl_xor(m, s, 64));
  __shared__ float red[8];
  const int w = t >> 6;
  if ((t & 63) == 0) red[w] = m;
  __syncthreads();
  m = fmaxf(fmaxf(red[0], red[1]), fmaxf(red[2], red[3]));
  float e0 = __expf(v0 - m), e1 = __expf(v1 - m);
  float e2 = __expf(v2 - m), e3 = __expf(v3 - m);
  float s = e0 + e1 + e2 + e3;
#pragma unroll
  for (int sh = 32; sh > 0; sh >>= 1) s += __shfl_xor(s, sh, 64);
  if ((t & 63) == 0) red[4 + w] = s;
  __syncthreads();
  const float inv = 1.0f / (red[4] + red[5] + red[6] + red[7]);
  ushort4 o;
  o.x = f2bf(e0 * inv); o.y = f2bf(e1 * inv);
  o.z = f2bf(e2 * inv); o.w = f2bf(e3 * inv);
  *(ushort4*)(p + t * 4) = o;
}

// ---------- host ----------
extern "C" void kernel_launch(void* const* d_in, const int* in_sizes, int n_in,
                              void* d_out, int out_size, void* d_ws, size_t ws_size,
                              hipStream_t stream) {
  const float* input   = (const float*)d_in[0];   // [8,512,4096]
  const float* context = (const float*)d_in[1];   // [8,512,1024]
  const float* pin_w   = (const float*)d_in[2];   // [512,512]  (N,K)
  const float* pin_b   = (const float*)d_in[3];
  const float* wq_w    = (const float*)d_in[4];   // [K=512,N=512]
  const float* wq_b    = (const float*)d_in[5];
  const float* wk_w    = (const float*)d_in[6];
  const float* wk_b    = (const float*)d_in[7];
  const float* wv_w    = (const float*)d_in[8];
  const float* wv_b    = (const float*)d_in[9];
  const float* pout_w  = (const float*)d_in[10];  // [512,1024] (N,K)
  const float* pout_b  = (const float*)d_in[11];

  char* ws = (char*)d_ws;
  size_t off = 0;
  auto alloc = [&](size_t bytes) -> void* {
    void* p = ws + off;
    off += (bytes + 255) & ~(size_t)255;
    return p;
  };
  bf16* pinw = (bf16*)alloc((size_t)512 * 512 * 2);
  bf16* poutw = (bf16*)alloc((size_t)512 * 1024 * 2);
  bf16* wqT = (bf16*)alloc((size_t)512 * 512 * 2);
  bf16* wkT = (bf16*)alloc((size_t)512 * 512 * 2);
  bf16* wvT = (bf16*)alloc((size_t)512 * 512 * 2);
  bf16* cat = (bf16*)alloc((size_t)32768 * 1024 * 2);  // [b*4096, 1024]: L=input^T, R=attn out
  bf16* ctxt = (bf16*)alloc((size_t)8192 * 512 * 2);   // [b*1024, 512]
  bf16* Xb  = (bf16*)alloc((size_t)32768 * 512 * 2);
  bf16* Qb  = (bf16*)alloc((size_t)32768 * 512 * 2);
  bf16* Kmb = (bf16*)alloc((size_t)8192 * 512 * 2);
  bf16* Vtb = (bf16*)alloc((size_t)8 * 512 * 1024 * 2);  // [b][512][1024] = V^T
  bf16* Sb  = (bf16*)alloc((size_t)8 * 4096 * 1024 * 2);

  dim3 blk(256);

  // weight prep
  convert_f32_bf16<<<1024, blk, 0, stream>>>(pin_w, pinw, 512 * 512);
  convert_f32_bf16<<<2048, blk, 0, stream>>>(pout_w, poutw, 512 * 1024);
  transpose_f32_to_bf16<<<dim3(16, 16, 1), blk, 0, stream>>>(wq_w, wqT, 512, 0, 0, 512, 0);
  transpose_f32_to_bf16<<<dim3(16, 16, 1), blk, 0, stream>>>(wk_w, wkT, 512, 0, 0, 512, 0);
  transpose_f32_to_bf16<<<dim3(16, 16, 1), blk, 0, stream>>>(wv_w, wvT, 512, 0, 0, 512, 0);
  // input -> cat left half ([b,4096,1024] cols 0..511)
  transpose_f32_to_bf16<<<dim3(128, 16, 8), blk, 0, stream>>>(
      input, cat, 4096, (long)512 * 4096, (long)4096 * 1024, 1024, 0);
  // context -> ctxt [b,1024,512]
  transpose_f32_to_bf16<<<dim3(32, 16, 8), blk, 0, stream>>>(
      context, ctxt, 1024, (long)512 * 1024, (long)1024 * 512, 512, 0);

  const float scale = 0.04419417382415922f;  // 512^-0.5

  // X = catL @ pinw^T + pin_b   [32768,512]
  gemm_bt_kernel<1, 1><<<dim3(4, 256, 1), blk, 0, stream>>>(
      cat, 0, 1024, pinw, 0, 512, Xb, 0, 512, pin_b, 1.f, 512);
  // Q = X @ wqT^T + wq_b        [32768,512]
  gemm_bt_kernel<1, 1><<<dim3(4, 256, 1), blk, 0, stream>>>(
      Xb, 0, 512, wqT, 0, 512, Qb, 0, 512, wq_b, 1.f, 512);
  // K = ctxt @ wkT^T + wk_b     [8192,512]
  gemm_bt_kernel<1, 1><<<dim3(4, 64, 1), blk, 0, stream>>>(
      ctxt, 0, 512, wkT, 0, 512, Kmb, 0, 512, wk_b, 1.f, 512);
  // Vt_b = wvT @ ctx_b^T + wv_b (per-row)   [8][512,1024]
  gemm_bt_kernel<1, 2><<<dim3(8, 4, 8), blk, 0, stream>>>(
      wvT, 0, 512, ctxt, (long)1024 * 512, 512, Vtb, (long)512 * 1024, 1024,
      wv_b, 1.f, 512);
  // S_b = scale * Q_b @ K_b^T   [8][4096,1024]
  gemm_bt_kernel<1, 0><<<dim3(8, 32, 8), blk, 0, stream>>>(
      Qb, (long)4096 * 512, 512, Kmb, (long)1024 * 512, 512, Sb,
      (long)4096 * 1024, 1024, nullptr, scale, 512);
  // softmax rows
  softmax_rows_1024<<<dim3(32768, 1, 1), blk, 0, stream>>>((u16*)Sb);
  // O_b = P_b @ Vt_b^T -> cat right half
  gemm_bt_kernel<1, 0><<<dim3(4, 32, 8), blk, 0, stream>>>(
      Sb, (long)4096 * 1024, 1024, Vtb, (long)512 * 1024, 1024,
      (void*)(cat + 512), (long)4096 * 1024, 1024, nullptr, 1.f, 1024);
  // out_b^T = poutw @ cat_b^T + pout_b (per-row) -> d_out [8][512][4096] fp32
  gemm_bt_kernel<0, 2><<<dim3(32, 4, 8), blk, 0, stream>>>(
      poutw, 0, 1024, cat, (long)4096 * 1024, 1024, d_out,
      (long)512 * 4096, 4096, pout_b, 1.f, 1024);
}

// Round 3
// 404.229 us; speedup vs baseline: 1.1249x; 1.1249x over previous
//
#include <hip/hip_runtime.h>
#include <hip/hip_bf16.h>

using bf16 = __hip_bfloat16;
typedef short s16x8 __attribute__((ext_vector_type(8)));
typedef float f32x4 __attribute__((ext_vector_type(4)));
typedef unsigned short u16;

// ---------- helpers ----------
__device__ __forceinline__ void gld_lds16(const void* g, void* l) {
  __builtin_amdgcn_global_load_lds(
      (const __attribute__((address_space(1))) void*)g,
      (__attribute__((address_space(3))) void*)l, 16, 0, 0);
}

__device__ __forceinline__ float bf2f(u16 u) {
  unsigned int x = ((unsigned int)u) << 16;
  return __builtin_bit_cast(float, x);
}

// ---------- fp32 -> bf16 elementwise convert ----------
__global__ __launch_bounds__(256) void convert_f32_bf16(
    const float* __restrict__ in, bf16* __restrict__ out, int n) {
  int i = blockIdx.x * 256 + threadIdx.x;
  if (i < n) out[i] = __float2bfloat16(in[i]);
}

// ---------- transpose [C][inner] fp32 -> [inner][out_ld] bf16 (out[p][c] = in[c][p]) ----------
__global__ __launch_bounds__(256) void transpose_f32_to_bf16(
    const float* __restrict__ in, bf16* __restrict__ out, int inner,
    long in_b, long out_b, int out_ld, int coloff) {
  __shared__ float tile[32][33];
  const int bx = blockIdx.x;
  const int by = blockIdx.y;
  const int bz = blockIdx.z;
  const int tx = threadIdx.x & 31;
  const int ty = threadIdx.x >> 5;
  const float* ib = in + (long)bz * in_b;
  bf16* ob = out + (long)bz * out_b;
#pragma unroll
  for (int i = 0; i < 4; ++i) {
    int r = ty + i * 8;
    tile[r][tx] = ib[(long)(by * 32 + r) * inner + bx * 32 + tx];
  }
  __syncthreads();
#pragma unroll
  for (int i = 0; i < 4; ++i) {
    int r = ty + i * 8;
    ob[(long)(bx * 32 + r) * out_ld + coloff + by * 32 + tx] =
        __float2bfloat16(tile[tx][r]);
  }
}

// ---------- bias combine: bQc[o] = qb[o] + sum_e pb[e]*wq[e,o] ----------
__global__ __launch_bounds__(256) void bias_combine(
    const float* __restrict__ pb, const float* __restrict__ wq,
    const float* __restrict__ qb, float* __restrict__ out) {
  int o = blockIdx.x * 256 + threadIdx.x;
  if (o >= 512) return;
  float s = qb[o];
  for (int e = 0; e < 512; ++e) s += pb[e] * wq[e * 512 + o];
  out[o] = s;
}

// ---------- row inverse-sum over 1024 bf16 (one wave per row) ----------
__global__ __launch_bounds__(256) void rowinv_1024(
    const u16* __restrict__ S, float* __restrict__ inv) {
  const int t = threadIdx.x;
  const int w = t >> 6, lane = t & 63;
  const long row = (long)blockIdx.x * 4 + w;
  const u16* p = S + row * 1024 + lane * 16;
  s16x8 a = *(const s16x8*)p;
  s16x8 b = *(const s16x8*)(p + 8);
  float s = 0.f;
#pragma unroll
  for (int i = 0; i < 8; ++i) s += bf2f((u16)a[i]) + bf2f((u16)b[i]);
#pragma unroll
  for (int sh = 32; sh > 0; sh >>= 1) s += __shfl_xor(s, sh, 64);
  if (lane == 0) inv[row] = 1.0f / s;
}

// ---------- GEMM: C[M,N] = alpha * A[M,K] @ B[N,K]^T (+bias) ----------
// BIAS_MODE: 0 none, 1 per-col, 2 per-row.
// EPI: 0 plain, 1 v=exp(alpha*acc), 2 v=acc*sc[bz*scb+row].
// 128x128 tile, BK=64, 4 waves 2x2, mfma 16x16x32 bf16.
// LDS XOR-swizzle: slot(r,chunk) holds global chunk (chunk ^ (r&7)); both sides.
template <int OUT_BF16, int BIAS_MODE, int EPI>
__global__ __launch_bounds__(256, 4) void gemm_bt_kernel(
    const bf16* __restrict__ A, long sAb, int lda,
    const bf16* __restrict__ B, long sBb, int ldb,
    void* __restrict__ Cp, long sCb, int ldc,
    const float* __restrict__ bias, const float* __restrict__ sc, long scb,
    float alpha, int K) {
  __shared__ __align__(16) bf16 tA[128 * 64];
  __shared__ __align__(16) bf16 tB[128 * 64];

  const int t = threadIdx.x;
  const int w = t >> 6;
  const int lane = t & 63;
  const int bn = blockIdx.x;
  const int bm = blockIdx.y;
  const int bz = blockIdx.z;

  const bf16* Ab = A + (long)bz * sAb;
  const bf16* Bb = B + (long)bz * sBb;

  const int srow = t >> 3;                          // 0..31
  const int schunk = (t & 7) ^ (srow & 7);          // pre-swizzled source chunk
  const int scol = schunk * 8;
  const long a_base = (long)(bm * 128 + srow) * lda + scol;
  const long b_base = (long)(bn * 128 + srow) * ldb + scol;
  char* lA = (char*)tA + w * 1024;  // linear LDS dest; HW adds lane*16
  char* lB = (char*)tB + w * 1024;

  const int wr = w >> 1, wc = w & 1;
  const int r15 = lane & 15;
  const int khalf = lane >> 4;  // 0..3
  f32x4 acc[4][4] = {};

  for (int kt = 0; kt < K; kt += 64) {
#pragma unroll
    for (int i = 0; i < 4; ++i) {
      gld_lds16(Ab + a_base + (long)(i * 32) * lda + kt, lA + i * 4096);
      gld_lds16(Bb + b_base + (long)(i * 32) * ldb + kt, lB + i * 4096);
    }
    __syncthreads();
#pragma unroll
    for (int kk = 0; kk < 2; ++kk) {
      const int chunk = kk * 4 + khalf;
      s16x8 af[4], bg[4];
#pragma unroll
      for (int m = 0; m < 4; ++m) {
        const int row = wr * 64 + m * 16 + r15;
        af[m] = *(const s16x8*)(tA + row * 64 + ((chunk ^ (row & 7)) * 8));
      }
#pragma unroll
      for (int n = 0; n < 4; ++n) {
        const int row = wc * 64 + n * 16 + r15;
        bg[n] = *(const s16x8*)(tB + row * 64 + ((chunk ^ (row & 7)) * 8));
      }
#pragma unroll
      for (int m = 0; m < 4; ++m)
#pragma unroll
        for (int n = 0; n < 4; ++n)
          acc[m][n] = __builtin_amdgcn_mfma_f32_16x16x32_bf16(af[m], bg[n],
                                                              acc[m][n], 0, 0, 0);
    }
    __syncthreads();
  }

  // epilogue: C/D layout col = lane&15, row = (lane>>4)*4 + j  [m89-verified]
#pragma unroll
  for (int m = 0; m < 4; ++m) {
    const int rb = bm * 128 + wr * 64 + m * 16 + (lane >> 4) * 4;
#pragma unroll
    for (int n = 0; n < 4; ++n) {
      const int col = bn * 128 + wc * 64 + n * 16 + (lane & 15);
      float bN = 0.f;
      if (BIAS_MODE == 1) bN = bias[col];
#pragma unroll
      for (int j = 0; j < 4; ++j) {
        const int row = rb + j;
        float v;
        if (EPI == 1) {
          v = __expf(acc[m][n][j] * alpha);
        } else if (EPI == 2) {
          v = acc[m][n][j] * sc[(long)bz * scb + row];
        } else {
          v = acc[m][n][j] * alpha;
          if (BIAS_MODE == 1) v += bN;
          if (BIAS_MODE == 2) v += bias[row];
        }
        const long off = (long)bz * sCb + (long)row * ldc + col;
        if (OUT_BF16)
          ((bf16*)Cp)[off] = __float2bfloat16(v);
        else
          ((float*)Cp)[off] = v;
      }
    }
  }
}

// ---------- host ----------
extern "C" void kernel_launch(void* const* d_in, const int* in_sizes, int n_in,
                              void* d_out, int out_size, void* d_ws, size_t ws_size,
                              hipStream_t stream) {
  const float* input   = (const float*)d_in[0];   // [8,512,4096]
  const float* context = (const float*)d_in[1];   // [8,512,1024]
  const float* pin_w   = (const float*)d_in[2];   // [512,512] [e][c]
  const float* pin_b   = (const float*)d_in[3];
  const float* wq_w    = (const float*)d_in[4];   // [512,512] [e][o]
  const float* wq_b    = (const float*)d_in[5];
  const float* wk_w    = (const float*)d_in[6];
  const float* wk_b    = (const float*)d_in[7];
  const float* wv_w    = (const float*)d_in[8];
  const float* wv_b    = (const float*)d_in[9];
  const float* pout_w  = (const float*)d_in[10];  // [512,1024] (N,K)
  const float* pout_b  = (const float*)d_in[11];

  char* ws = (char*)d_ws;
  size_t off = 0;
  auto alloc = [&](size_t bytes) -> void* {
    void* p = ws + off;
    off += (bytes + 255) & ~(size_t)255;
    return p;
  };
  bf16* poutw = (bf16*)alloc((size_t)512 * 1024 * 2);
  bf16* wqT  = (bf16*)alloc((size_t)512 * 512 * 2);
  bf16* wkT  = (bf16*)alloc((size_t)512 * 512 * 2);
  bf16* wvT  = (bf16*)alloc((size_t)512 * 512 * 2);
  bf16* pinT = (bf16*)alloc((size_t)512 * 512 * 2);
  bf16* WQc  = (bf16*)alloc((size_t)512 * 512 * 2);
  float* bQc = (float*)alloc((size_t)512 * 4);
  bf16* cat  = (bf16*)alloc((size_t)32768 * 1024 * 2);  // L=input^T, R=attn out
  bf16* ctxt = (bf16*)alloc((size_t)8192 * 512 * 2);    // [b*1024, 512]
  bf16* Qb   = (bf16*)alloc((size_t)32768 * 512 * 2);
  bf16* Kmb  = (bf16*)alloc((size_t)8192 * 512 * 2);
  bf16* Vtb  = (bf16*)alloc((size_t)8 * 512 * 1024 * 2);  // [b][512][1024] = V^T
  bf16* Sb   = (bf16*)alloc((size_t)8 * 4096 * 1024 * 2); // expS
  float* rinv = (float*)alloc((size_t)32768 * 4);

  dim3 blk(256);

  // weight prep
  convert_f32_bf16<<<2048, blk, 0, stream>>>(pout_w, poutw, 512 * 1024);
  transpose_f32_to_bf16<<<dim3(16, 16, 1), blk, 0, stream>>>(wq_w, wqT, 512, 0, 0, 512, 0);
  transpose_f32_to_bf16<<<dim3(16, 16, 1), blk, 0, stream>>>(wk_w, wkT, 512, 0, 0, 512, 0);
  transpose_f32_to_bf16<<<dim3(16, 16, 1), blk, 0, stream>>>(wv_w, wvT, 512, 0, 0, 512, 0);
  transpose_f32_to_bf16<<<dim3(16, 16, 1), blk, 0, stream>>>(pin_w, pinT, 512, 0, 0, 512, 0);
  bias_combine<<<2, blk, 0, stream>>>(pin_b, wq_w, wq_b, bQc);
  // input -> cat left half
  transpose_f32_to_bf16<<<dim3(128, 16, 8), blk, 0, stream>>>(
      input, cat, 4096, (long)512 * 4096, (long)4096 * 1024, 1024, 0);
  // context -> ctxt
  transpose_f32_to_bf16<<<dim3(32, 16, 8), blk, 0, stream>>>(
      context, ctxt, 1024, (long)512 * 1024, (long)1024 * 512, 512, 0);

  const float scale = 0.04419417382415922f;  // 512^-0.5

  // WQc[o,c] = sum_e wq[e,o]*pin_w[e,c]  -> [512,512]
  gemm_bt_kernel<1, 0, 0><<<dim3(4, 4, 1), blk, 0, stream>>>(
      wqT, 0, 512, pinT, 0, 512, WQc, 0, 512, nullptr, nullptr, 0, 1.f, 512);
  // Q = catL @ WQc^T + bQc   [32768,512]
  gemm_bt_kernel<1, 1, 0><<<dim3(4, 256, 1), blk, 0, stream>>>(
      cat, 0, 1024, WQc, 0, 512, Qb, 0, 512, bQc, nullptr, 0, 1.f, 512);
  // K = ctxt @ wkT^T + wk_b  [8192,512]
  gemm_bt_kernel<1, 1, 0><<<dim3(4, 64, 1), blk, 0, stream>>>(
      ctxt, 0, 512, wkT, 0, 512, Kmb, 0, 512, wk_b, nullptr, 0, 1.f, 512);
  // Vt_b = wvT @ ctx_b^T + wv_b (per-row)  [8][512,1024]
  gemm_bt_kernel<1, 2, 0><<<dim3(8, 4, 8), blk, 0, stream>>>(
      wvT, 0, 512, ctxt, (long)1024 * 512, 512, Vtb, (long)512 * 1024, 1024,
      wv_b, nullptr, 0, 1.f, 512);
  // expS_b = exp(scale * Q_b @ K_b^T)  [8][4096,1024]
  gemm_bt_kernel<1, 0, 1><<<dim3(8, 32, 8), blk, 0, stream>>>(
      Qb, (long)4096 * 512, 512, Kmb, (long)1024 * 512, 512, Sb,
      (long)4096 * 1024, 1024, nullptr, nullptr, 0, scale, 512);
  // row inverse sums
  rowinv_1024<<<dim3(8192, 1, 1), blk, 0, stream>>>((const u16*)Sb, rinv);
  // O_b = (expS_b @ Vt_b^T) * rinv[row] -> cat right half
  gemm_bt_kernel<1, 0, 2><<<dim3(4, 32, 8), blk, 0, stream>>>(
      Sb, (long)4096 * 1024, 1024, Vtb, (long)512 * 1024, 1024,
      (void*)(cat + 512), (long)4096 * 1024, 1024, nullptr, rinv, 4096, 1.f, 1024);
  // out_b^T = poutw @ cat_b^T + pout_b (per-row) -> d_out [8][512][4096] fp32
  gemm_bt_kernel<0, 2, 0><<<dim3(32, 4, 8), blk, 0, stream>>>(
      poutw, 0, 1024, cat, (long)4096 * 1024, 1024, d_out,
      (long)512 * 4096, 4096, pout_b, nullptr, 0, 1.f, 1024);
}

// Round 4
// 380.572 us; speedup vs baseline: 1.1948x; 1.0622x over previous
//
#include <hip/hip_runtime.h>
#include <hip/hip_bf16.h>

using bf16 = __hip_bfloat16;
typedef short s16x8 __attribute__((ext_vector_type(8)));
typedef float f32x4 __attribute__((ext_vector_type(4)));
typedef unsigned short u16;

// ---------- helpers ----------
__device__ __forceinline__ void gld_lds16(const void* g, void* l) {
  __builtin_amdgcn_global_load_lds(
      (const __attribute__((address_space(1))) void*)g,
      (__attribute__((address_space(3))) void*)l, 16, 0, 0);
}

__device__ __forceinline__ float bf2f(u16 u) {
  unsigned int x = ((unsigned int)u) << 16;
  return __builtin_bit_cast(float, x);
}

// ---------- fp32 -> bf16 elementwise convert ----------
__global__ __launch_bounds__(256) void convert_f32_bf16(
    const float* __restrict__ in, bf16* __restrict__ out, int n) {
  int i = blockIdx.x * 256 + threadIdx.x;
  if (i < n) out[i] = __float2bfloat16(in[i]);
}

// ---------- zero fp32 ----------
__global__ __launch_bounds__(256) void zero_f32(float* __restrict__ p, int n) {
  int i = blockIdx.x * 256 + threadIdx.x;
  if (i < n) p[i] = 0.f;
}

// ---------- transpose [C][inner] fp32 -> [inner][out_ld] bf16 (out[p][c] = in[c][p]) ----------
__global__ __launch_bounds__(256) void transpose_f32_to_bf16(
    const float* __restrict__ in, bf16* __restrict__ out, int inner,
    long in_b, long out_b, int out_ld, int coloff) {
  __shared__ float tile[32][33];
  const int bx = blockIdx.x;
  const int by = blockIdx.y;
  const int bz = blockIdx.z;
  const int tx = threadIdx.x & 31;
  const int ty = threadIdx.x >> 5;
  const float* ib = in + (long)bz * in_b;
  bf16* ob = out + (long)bz * out_b;
#pragma unroll
  for (int i = 0; i < 4; ++i) {
    int r = ty + i * 8;
    tile[r][tx] = ib[(long)(by * 32 + r) * inner + bx * 32 + tx];
  }
  __syncthreads();
#pragma unroll
  for (int i = 0; i < 4; ++i) {
    int r = ty + i * 8;
    ob[(long)(bx * 32 + r) * out_ld + coloff + by * 32 + tx] =
        __float2bfloat16(tile[tx][r]);
  }
}

// ---------- bias combine: bQc[o] = qb[o] + sum_e pb[e]*wq[e,o] ----------
__global__ __launch_bounds__(256) void bias_combine(
    const float* __restrict__ pb, const float* __restrict__ wq,
    const float* __restrict__ qb, float* __restrict__ out) {
  int o = blockIdx.x * 256 + threadIdx.x;
  if (o >= 512) return;
  float s = qb[o];
  for (int e = 0; e < 512; ++e) s += pb[e] * wq[e * 512 + o];
  out[o] = s;
}

// ---------- GEMM: C[M,N] = alpha * A[M,K] @ B[N,K]^T (+bias) ----------
// BIAS_MODE: 0 none, 1 per-col, 2 per-row.
// EPI: 0 plain, 1 v=exp(alpha*acc) + rowsum atomicAdd into sc,
//      2 v=acc/sc[bz*scb+row].
// 128x128 tile, BK=64, 4 waves 2x2, mfma 16x16x32 bf16.
// LDS XOR-swizzle both sides (r1-verified, conflicts=0).
// Grid is 1-D; kernel applies chunked-bijective XCD swizzle (m204) then
// decomposes wgid -> (bn, bm, bz) with bn fastest (panel-sharers contiguous
// -> same XCD L2).
template <int OUT_BF16, int BIAS_MODE, int EPI>
__global__ __launch_bounds__(256, 4) void gemm_bt_kernel(
    const bf16* __restrict__ A, long sAb, int lda,
    const bf16* __restrict__ B, long sBb, int ldb,
    void* __restrict__ Cp, long sCb, int ldc,
    const float* __restrict__ bias, float* __restrict__ sc, long scb,
    float alpha, int K, int lgx, int lgy) {
  __shared__ __align__(16) bf16 tA[128 * 64];
  __shared__ __align__(16) bf16 tB[128 * 64];

  // XCD-chunked bijective remap
  const int nwg = gridDim.x;
  const int orig = blockIdx.x;
  const int q = nwg >> 3, r = nwg & 7;
  const int xcd = orig & 7, local = orig >> 3;
  const int wgid = (xcd < r ? xcd * (q + 1) : r * (q + 1) + (xcd - r) * q) + local;
  const int bn = wgid & ((1 << lgx) - 1);
  const int tmp = wgid >> lgx;
  const int bm = tmp & ((1 << lgy) - 1);
  const int bz = tmp >> lgy;

  const int t = threadIdx.x;
  const int w = t >> 6;
  const int lane = t & 63;

  const bf16* Ab = A + (long)bz * sAb;
  const bf16* Bb = B + (long)bz * sBb;

  const int srow = t >> 3;                  // 0..31
  const int schunk = (t & 7) ^ (srow & 7);  // pre-swizzled source chunk
  const int scol = schunk * 8;
  const long a_base = (long)(bm * 128 + srow) * lda + scol;
  const long b_base = (long)(bn * 128 + srow) * ldb + scol;
  char* lA = (char*)tA + w * 1024;  // linear LDS dest; HW adds lane*16
  char* lB = (char*)tB + w * 1024;

  const int wr = w >> 1, wc = w & 1;
  const int r15 = lane & 15;
  const int khalf = lane >> 4;  // 0..3
  f32x4 acc[4][4] = {};

  for (int kt = 0; kt < K; kt += 64) {
#pragma unroll
    for (int i = 0; i < 4; ++i) {
      gld_lds16(Ab + a_base + (long)(i * 32) * lda + kt, lA + i * 4096);
      gld_lds16(Bb + b_base + (long)(i * 32) * ldb + kt, lB + i * 4096);
    }
    __syncthreads();
#pragma unroll
    for (int kk = 0; kk < 2; ++kk) {
      const int chunk = kk * 4 + khalf;
      s16x8 af[4], bg[4];
#pragma unroll
      for (int m = 0; m < 4; ++m) {
        const int row = wr * 64 + m * 16 + r15;
        af[m] = *(const s16x8*)(tA + row * 64 + ((chunk ^ (row & 7)) * 8));
      }
#pragma unroll
      for (int n = 0; n < 4; ++n) {
        const int row = wc * 64 + n * 16 + r15;
        bg[n] = *(const s16x8*)(tB + row * 64 + ((chunk ^ (row & 7)) * 8));
      }
#pragma unroll
      for (int m = 0; m < 4; ++m)
#pragma unroll
        for (int n = 0; n < 4; ++n)
          acc[m][n] = __builtin_amdgcn_mfma_f32_16x16x32_bf16(af[m], bg[n],
                                                              acc[m][n], 0, 0, 0);
    }
    __syncthreads();
  }

  // epilogue: C/D layout col = lane&15, row = (lane>>4)*4 + j  [m89-verified]
#pragma unroll
  for (int m = 0; m < 4; ++m) {
    const int rb = bm * 128 + wr * 64 + m * 16 + (lane >> 4) * 4;
    float rin[4];
    if (EPI == 2) {
#pragma unroll
      for (int j = 0; j < 4; ++j) rin[j] = 1.0f / sc[(long)bz * scb + rb + j];
    }
    float rs[4] = {0.f, 0.f, 0.f, 0.f};
#pragma unroll
    for (int n = 0; n < 4; ++n) {
      const int col = bn * 128 + wc * 64 + n * 16 + r15;
      float bN = 0.f;
      if (BIAS_MODE == 1) bN = bias[col];
#pragma unroll
      for (int j = 0; j < 4; ++j) {
        const int row = rb + j;
        float v;
        if (EPI == 1) {
          v = __expf(acc[m][n][j] * alpha);
          rs[j] += v;
        } else if (EPI == 2) {
          v = acc[m][n][j] * rin[j];
        } else {
          v = acc[m][n][j] * alpha;
          if (BIAS_MODE == 1) v += bN;
          if (BIAS_MODE == 2) v += bias[row];
        }
        const long off = (long)bz * sCb + (long)row * ldc + col;
        if (OUT_BF16)
          ((bf16*)Cp)[off] = __float2bfloat16(v);
        else
          ((float*)Cp)[off] = v;
      }
    }
    if (EPI == 1) {
      // reduce the 16 col-lanes (r15), then one atomic per row per wave-half
#pragma unroll
      for (int j = 0; j < 4; ++j) {
        float s = rs[j];
#pragma unroll
        for (int sh = 1; sh < 16; sh <<= 1) s += __shfl_xor(s, sh, 64);
        if (r15 == 0) atomicAdd(sc + (long)bz * scb + rb + j, s);
      }
    }
  }
}

// ---------- host ----------
extern "C" void kernel_launch(void* const* d_in, const int* in_sizes, int n_in,
                              void* d_out, int out_size, void* d_ws, size_t ws_size,
                              hipStream_t stream) {
  const float* input   = (const float*)d_in[0];   // [8,512,4096]
  const float* context = (const float*)d_in[1];   // [8,512,1024]
  const float* pin_w   = (const float*)d_in[2];   // [512,512] [e][c]
  const float* pin_b   = (const float*)d_in[3];
  const float* wq_w    = (const float*)d_in[4];   // [512,512] [e][o]
  const float* wq_b    = (const float*)d_in[5];
  const float* wk_w    = (const float*)d_in[6];
  const float* wk_b    = (const float*)d_in[7];
  const float* wv_w    = (const float*)d_in[8];
  const float* wv_b    = (const float*)d_in[9];
  const float* pout_w  = (const float*)d_in[10];  // [512,1024] (N,K)
  const float* pout_b  = (const float*)d_in[11];

  char* ws = (char*)d_ws;
  size_t off = 0;
  auto alloc = [&](size_t bytes) -> void* {
    void* p = ws + off;
    off += (bytes + 255) & ~(size_t)255;
    return p;
  };
  bf16* poutw = (bf16*)alloc((size_t)512 * 1024 * 2);
  bf16* wqT  = (bf16*)alloc((size_t)512 * 512 * 2);
  bf16* wkT  = (bf16*)alloc((size_t)512 * 512 * 2);
  bf16* wvT  = (bf16*)alloc((size_t)512 * 512 * 2);
  bf16* pinT = (bf16*)alloc((size_t)512 * 512 * 2);
  bf16* WQc  = (bf16*)alloc((size_t)512 * 512 * 2);
  float* bQc = (float*)alloc((size_t)512 * 4);
  bf16* cat  = (bf16*)alloc((size_t)32768 * 1024 * 2);  // L=input^T, R=attn out
  bf16* ctxt = (bf16*)alloc((size_t)8192 * 512 * 2);    // [b*1024, 512]
  bf16* Qb   = (bf16*)alloc((size_t)32768 * 512 * 2);
  bf16* Kmb  = (bf16*)alloc((size_t)8192 * 512 * 2);
  bf16* Vtb  = (bf16*)alloc((size_t)8 * 512 * 1024 * 2);  // [b][512][1024] = V^T
  bf16* Sb   = (bf16*)alloc((size_t)8 * 4096 * 1024 * 2); // expS
  float* rsum = (float*)alloc((size_t)32768 * 4);

  dim3 blk(256);

  // weight prep
  convert_f32_bf16<<<2048, blk, 0, stream>>>(pout_w, poutw, 512 * 1024);
  zero_f32<<<128, blk, 0, stream>>>(rsum, 32768);
  transpose_f32_to_bf16<<<dim3(16, 16, 1), blk, 0, stream>>>(wq_w, wqT, 512, 0, 0, 512, 0);
  transpose_f32_to_bf16<<<dim3(16, 16, 1), blk, 0, stream>>>(wk_w, wkT, 512, 0, 0, 512, 0);
  transpose_f32_to_bf16<<<dim3(16, 16, 1), blk, 0, stream>>>(wv_w, wvT, 512, 0, 0, 512, 0);
  transpose_f32_to_bf16<<<dim3(16, 16, 1), blk, 0, stream>>>(pin_w, pinT, 512, 0, 0, 512, 0);
  bias_combine<<<2, blk, 0, stream>>>(pin_b, wq_w, wq_b, bQc);
  // input -> cat left half
  transpose_f32_to_bf16<<<dim3(128, 16, 8), blk, 0, stream>>>(
      input, cat, 4096, (long)512 * 4096, (long)4096 * 1024, 1024, 0);
  // context -> ctxt
  transpose_f32_to_bf16<<<dim3(32, 16, 8), blk, 0, stream>>>(
      context, ctxt, 1024, (long)512 * 1024, (long)1024 * 512, 512, 0);

  const float scale = 0.04419417382415922f;  // 512^-0.5

  // WQc[o,c] = sum_e wq[e,o]*pin_w[e,c]  -> [512,512]   grid 4x4
  gemm_bt_kernel<1, 0, 0><<<dim3(16), blk, 0, stream>>>(
      wqT, 0, 512, pinT, 0, 512, WQc, 0, 512, nullptr, nullptr, 0, 1.f, 512, 2, 2);
  // Q = catL @ WQc^T + bQc   [32768,512]   grid 4x256
  gemm_bt_kernel<1, 1, 0><<<dim3(1024), blk, 0, stream>>>(
      cat, 0, 1024, WQc, 0, 512, Qb, 0, 512, bQc, nullptr, 0, 1.f, 512, 2, 8);
  // K = ctxt @ wkT^T + wk_b  [8192,512]   grid 4x64
  gemm_bt_kernel<1, 1, 0><<<dim3(256), blk, 0, stream>>>(
      ctxt, 0, 512, wkT, 0, 512, Kmb, 0, 512, wk_b, nullptr, 0, 1.f, 512, 2, 6);
  // Vt_b = wvT @ ctx_b^T + wv_b (per-row)  [8][512,1024]   grid 8x4x8
  gemm_bt_kernel<1, 2, 0><<<dim3(256), blk, 0, stream>>>(
      wvT, 0, 512, ctxt, (long)1024 * 512, 512, Vtb, (long)512 * 1024, 1024,
      wv_b, nullptr, 0, 1.f, 512, 3, 2);
  // expS_b = exp(scale * Q_b @ K_b^T), rowsum -> rsum  [8][4096,1024]  grid 8x32x8
  gemm_bt_kernel<1, 0, 1><<<dim3(2048), blk, 0, stream>>>(
      Qb, (long)4096 * 512, 512, Kmb, (long)1024 * 512, 512, Sb,
      (long)4096 * 1024, 1024, nullptr, rsum, 4096, scale, 512, 3, 5);
  // O_b = (expS_b @ Vt_b^T) / rsum[row] -> cat right half   grid 4x32x8
  gemm_bt_kernel<1, 0, 2><<<dim3(1024), blk, 0, stream>>>(
      Sb, (long)4096 * 1024, 1024, Vtb, (long)512 * 1024, 1024,
      (void*)(cat + 512), (long)4096 * 1024, 1024, nullptr, rsum, 4096, 1.f,
      1024, 2, 5);
  // out_b^T = poutw @ cat_b^T + pout_b (per-row) -> d_out [8][512][4096] fp32
  // grid 32x4x8
  gemm_bt_kernel<0, 2, 0><<<dim3(1024), blk, 0, stream>>>(
      poutw, 0, 1024, cat, (long)4096 * 1024, 1024, d_out,
      (long)512 * 4096, 4096, pout_b, nullptr, 0, 1.f, 1024, 5, 2);
}

// Round 5
// 365.568 us; speedup vs baseline: 1.2439x; 1.0410x over previous
//
#include <hip/hip_runtime.h>
#include <hip/hip_bf16.h>

using bf16 = __hip_bfloat16;
typedef short s16x8 __attribute__((ext_vector_type(8)));
typedef float f32x4 __attribute__((ext_vector_type(4)));
typedef unsigned short u16;

// ---------- helpers ----------
__device__ __forceinline__ void gld_lds16(const void* g, void* l) {
  __builtin_amdgcn_global_load_lds(
      (const __attribute__((address_space(1))) void*)g,
      (__attribute__((address_space(3))) void*)l, 16, 0, 0);
}

__device__ __forceinline__ float bf2f(u16 u) {
  unsigned int x = ((unsigned int)u) << 16;
  return __builtin_bit_cast(float, x);
}

// ---------- fp32 -> bf16 elementwise convert ----------
__global__ __launch_bounds__(256) void convert_f32_bf16(
    const float* __restrict__ in, bf16* __restrict__ out, int n) {
  int i = blockIdx.x * 256 + threadIdx.x;
  if (i < n) out[i] = __float2bfloat16(in[i]);
}

// ---------- zero fp32 ----------
__global__ __launch_bounds__(256) void zero_f32(float* __restrict__ p, int n) {
  int i = blockIdx.x * 256 + threadIdx.x;
  if (i < n) p[i] = 0.f;
}

// ---------- transpose [C][inner] fp32 -> [inner][out_ld] bf16 ----------
__global__ __launch_bounds__(256) void transpose_f32_to_bf16(
    const float* __restrict__ in, bf16* __restrict__ out, int inner,
    long in_b, long out_b, int out_ld, int coloff) {
  __shared__ float tile[32][33];
  const int bx = blockIdx.x;
  const int by = blockIdx.y;
  const int bz = blockIdx.z;
  const int tx = threadIdx.x & 31;
  const int ty = threadIdx.x >> 5;
  const float* ib = in + (long)bz * in_b;
  bf16* ob = out + (long)bz * out_b;
#pragma unroll
  for (int i = 0; i < 4; ++i) {
    int r = ty + i * 8;
    tile[r][tx] = ib[(long)(by * 32 + r) * inner + bx * 32 + tx];
  }
  __syncthreads();
#pragma unroll
  for (int i = 0; i < 4; ++i) {
    int r = ty + i * 8;
    ob[(long)(bx * 32 + r) * out_ld + coloff + by * 32 + tx] =
        __float2bfloat16(tile[tx][r]);
  }
}

// ---------- fused 4x [512,512] weight transpose -> bf16 ----------
__global__ __launch_bounds__(256) void transpose_w4(
    const float* __restrict__ w0, const float* __restrict__ w1,
    const float* __restrict__ w2, const float* __restrict__ w3,
    bf16* __restrict__ o0, bf16* __restrict__ o1,
    bf16* __restrict__ o2, bf16* __restrict__ o3) {
  __shared__ float tile[32][33];
  const float* in;
  bf16* out;
  switch (blockIdx.z) {
    case 0: in = w0; out = o0; break;
    case 1: in = w1; out = o1; break;
    case 2: in = w2; out = o2; break;
    default: in = w3; out = o3; break;
  }
  const int bx = blockIdx.x, by = blockIdx.y;
  const int tx = threadIdx.x & 31, ty = threadIdx.x >> 5;
#pragma unroll
  for (int i = 0; i < 4; ++i) {
    int r = ty + i * 8;
    tile[r][tx] = in[(long)(by * 32 + r) * 512 + bx * 32 + tx];
  }
  __syncthreads();
#pragma unroll
  for (int i = 0; i < 4; ++i) {
    int r = ty + i * 8;
    out[(long)(bx * 32 + r) * 512 + by * 32 + tx] = __float2bfloat16(tile[tx][r]);
  }
}

// ---------- bias combine: bQc[o] = qb[o] + sum_e pb[e]*wq[e,o] ----------
__global__ __launch_bounds__(256) void bias_combine(
    const float* __restrict__ pb, const float* __restrict__ wq,
    const float* __restrict__ qb, float* __restrict__ out) {
  int o = blockIdx.x * 256 + threadIdx.x;
  if (o >= 512) return;
  float s = qb[o];
  for (int e = 0; e < 512; ++e) s += pb[e] * wq[e * 512 + o];
  out[o] = s;
}

// ======================================================================
// 128x128 GEMM (verified r3 structure) — kept for the small GEMMs.
// ======================================================================
template <int OUT_BF16, int BIAS_MODE, int EPI>
__global__ __launch_bounds__(256, 4) void gemm_bt_kernel(
    const bf16* __restrict__ A, long sAb, int lda,
    const bf16* __restrict__ B, long sBb, int ldb,
    void* __restrict__ Cp, long sCb, int ldc,
    const float* __restrict__ bias, float* __restrict__ sc, long scb,
    float alpha, int K, int lgx, int lgy) {
  __shared__ __align__(16) bf16 tA[128 * 64];
  __shared__ __align__(16) bf16 tB[128 * 64];

  const int nwg = gridDim.x;
  const int orig = blockIdx.x;
  const int q = nwg >> 3, r = nwg & 7;
  const int xcd = orig & 7, local = orig >> 3;
  const int wgid = (xcd < r ? xcd * (q + 1) : r * (q + 1) + (xcd - r) * q) + local;
  const int bn = wgid & ((1 << lgx) - 1);
  const int tmp = wgid >> lgx;
  const int bm = tmp & ((1 << lgy) - 1);
  const int bz = tmp >> lgy;

  const int t = threadIdx.x;
  const int w = t >> 6;
  const int lane = t & 63;

  const bf16* Ab = A + (long)bz * sAb;
  const bf16* Bb = B + (long)bz * sBb;

  const int srow = t >> 3;
  const int scol = ((t & 7) ^ (srow & 7)) * 8;
  const long a_base = (long)(bm * 128 + srow) * lda + scol;
  const long b_base = (long)(bn * 128 + srow) * ldb + scol;
  char* lA = (char*)tA + w * 1024;
  char* lB = (char*)tB + w * 1024;

  const int wr = w >> 1, wc = w & 1;
  const int r15 = lane & 15;
  const int khalf = lane >> 4;
  f32x4 acc[4][4] = {};

  for (int kt = 0; kt < K; kt += 64) {
#pragma unroll
    for (int i = 0; i < 4; ++i) {
      gld_lds16(Ab + a_base + (long)(i * 32) * lda + kt, lA + i * 4096);
      gld_lds16(Bb + b_base + (long)(i * 32) * ldb + kt, lB + i * 4096);
    }
    __syncthreads();
#pragma unroll
    for (int kk = 0; kk < 2; ++kk) {
      const int chunk = kk * 4 + khalf;
      s16x8 af[4], bg[4];
#pragma unroll
      for (int m = 0; m < 4; ++m) {
        const int row = wr * 64 + m * 16 + r15;
        af[m] = *(const s16x8*)(tA + row * 64 + ((chunk ^ (row & 7)) * 8));
      }
#pragma unroll
      for (int n = 0; n < 4; ++n) {
        const int row = wc * 64 + n * 16 + r15;
        bg[n] = *(const s16x8*)(tB + row * 64 + ((chunk ^ (row & 7)) * 8));
      }
#pragma unroll
      for (int m = 0; m < 4; ++m)
#pragma unroll
        for (int n = 0; n < 4; ++n)
          acc[m][n] = __builtin_amdgcn_mfma_f32_16x16x32_bf16(af[m], bg[n],
                                                              acc[m][n], 0, 0, 0);
    }
    __syncthreads();
  }

#pragma unroll
  for (int m = 0; m < 4; ++m) {
    const int rb = bm * 128 + wr * 64 + m * 16 + (lane >> 4) * 4;
    float rin[4];
    if (EPI == 2) {
#pragma unroll
      for (int j = 0; j < 4; ++j) rin[j] = 1.0f / sc[(long)bz * scb + rb + j];
    }
    float rs[4] = {0.f, 0.f, 0.f, 0.f};
#pragma unroll
    for (int n = 0; n < 4; ++n) {
      const int col = bn * 128 + wc * 64 + n * 16 + r15;
      float bN = 0.f;
      if (BIAS_MODE == 1) bN = bias[col];
#pragma unroll
      for (int j = 0; j < 4; ++j) {
        const int row = rb + j;
        float v;
        if (EPI == 1) {
          v = __expf(acc[m][n][j] * alpha);
          rs[j] += v;
        } else if (EPI == 2) {
          v = acc[m][n][j] * rin[j];
        } else {
          v = acc[m][n][j] * alpha;
          if (BIAS_MODE == 1) v += bN;
          if (BIAS_MODE == 2) v += bias[row];
        }
        const long off = (long)bz * sCb + (long)row * ldc + col;
        if (OUT_BF16)
          ((bf16*)Cp)[off] = __float2bfloat16(v);
        else
          ((float*)Cp)[off] = v;
      }
    }
    if (EPI == 1) {
#pragma unroll
      for (int j = 0; j < 4; ++j) {
        float s = rs[j];
#pragma unroll
        for (int sh = 1; sh < 16; sh <<= 1) s += __shfl_xor(s, sh, 64);
        if (r15 == 0) atomicAdd(sc + (long)bz * scb + rb + j, s);
      }
    }
  }
}

// ======================================================================
// 256x256 2-phase double-buffered GEMM — the big-GEMM workhorse.
// 512 threads = 8 waves (2M x 4N), per-wave 128x64 out, BK=64.
// LDS 128 KiB dynamic: tA[2][256*64] + tB[2][256*64] bf16.
// Stage-ahead: K-tile t+1's global_load_lds issued before computing t;
// one __syncthreads (full drain) per K-tile. Race-free by construction.
// Same XOR swizzle (0-conflict, r3-verified) + T1 XCD remap.
// ======================================================================
template <int OUT_BF16, int BIAS_MODE, int EPI>
__global__ __launch_bounds__(512) void gemm256_kernel(
    const bf16* __restrict__ A, long sAb, int lda,
    const bf16* __restrict__ B, long sBb, int ldb,
    void* __restrict__ Cp, long sCb, int ldc,
    const float* __restrict__ bias, float* __restrict__ sc, long scb,
    float alpha, int K, int lgx, int lgy) {
  extern __shared__ __align__(16) char smem[];
  bf16* tA = (bf16*)smem;             // [2][16384]
  bf16* tB = (bf16*)(smem + 65536);   // [2][16384]

  const int nwg = gridDim.x;
  const int orig = blockIdx.x;
  const int q = nwg >> 3, r = nwg & 7;
  const int xcd = orig & 7, local = orig >> 3;
  const int wgid = (xcd < r ? xcd * (q + 1) : r * (q + 1) + (xcd - r) * q) + local;
  const int bn = wgid & ((1 << lgx) - 1);
  const int tmp = wgid >> lgx;
  const int bm = tmp & ((1 << lgy) - 1);
  const int bz = tmp >> lgy;

  const int t = threadIdx.x;
  const int w = t >> 6;
  const int lane = t & 63;
  const int wr = w >> 2, wc = w & 3;
  const int r15 = lane & 15;
  const int khalf = lane >> 4;

  const bf16* Ab = A + (long)bz * sAb;
  const bf16* Bb = B + (long)bz * sBb;

  const int srow = t >> 3;                       // 0..63
  const int scol = ((t & 7) ^ (srow & 7)) * 8;   // pre-swizzled source chunk
  const long a_base = (long)(bm * 256 + srow) * lda + scol;
  const long b_base = (long)(bn * 256 + srow) * ldb + scol;

  f32x4 acc[8][4] = {};

  auto STAGE = [&](int buf, int kt) {
    char* dA = (char*)(tA + buf * 16384) + w * 1024;
    char* dB = (char*)(tB + buf * 16384) + w * 1024;
#pragma unroll
    for (int i = 0; i < 4; ++i)
      gld_lds16(Ab + a_base + (long)(i * 64) * lda + kt, dA + i * 8192);
#pragma unroll
    for (int i = 0; i < 4; ++i)
      gld_lds16(Bb + b_base + (long)(i * 64) * ldb + kt, dB + i * 8192);
  };

  auto COMPUTE = [&](int buf) {
    const bf16* tAc = tA + buf * 16384;
    const bf16* tBc = tB + buf * 16384;
    s16x8 bg[2][4];
#pragma unroll
    for (int ks = 0; ks < 2; ++ks)
#pragma unroll
      for (int n = 0; n < 4; ++n) {
        const int row = wc * 64 + n * 16 + r15;
        bg[ks][n] =
            *(const s16x8*)(tBc + row * 64 + (((ks * 4 + khalf) ^ (row & 7)) * 8));
      }
#pragma unroll
    for (int m = 0; m < 8; ++m) {
      const int row = wr * 128 + m * 16 + r15;
      const s16x8 a0 =
          *(const s16x8*)(tAc + row * 64 + ((khalf ^ (row & 7)) * 8));
      const s16x8 a1 =
          *(const s16x8*)(tAc + row * 64 + (((4 + khalf) ^ (row & 7)) * 8));
#pragma unroll
      for (int n = 0; n < 4; ++n)
        acc[m][n] =
            __builtin_amdgcn_mfma_f32_16x16x32_bf16(a0, bg[0][n], acc[m][n], 0, 0, 0);
#pragma unroll
      for (int n = 0; n < 4; ++n)
        acc[m][n] =
            __builtin_amdgcn_mfma_f32_16x16x32_bf16(a1, bg[1][n], acc[m][n], 0, 0, 0);
    }
  };

  STAGE(0, 0);
  __syncthreads();
  int cur = 0;
  for (int kt = 64; kt < K; kt += 64) {
    STAGE(cur ^ 1, kt);   // next tile's loads in flight during compute
    COMPUTE(cur);
    __syncthreads();      // drain: stage landed, reads done
    cur ^= 1;
  }
  COMPUTE(cur);

  // epilogue: C/D layout col = lane&15, row = (lane>>4)*4 + j
#pragma unroll
  for (int m = 0; m < 8; ++m) {
    const int rb = bm * 256 + wr * 128 + m * 16 + (lane >> 4) * 4;
    float rin[4];
    if (EPI == 2) {
#pragma unroll
      for (int j = 0; j < 4; ++j) rin[j] = 1.0f / sc[(long)bz * scb + rb + j];
    }
    float rs[4] = {0.f, 0.f, 0.f, 0.f};
#pragma unroll
    for (int n = 0; n < 4; ++n) {
      const int col = bn * 256 + wc * 64 + n * 16 + r15;
      float bN = 0.f;
      if (BIAS_MODE == 1) bN = bias[col];
#pragma unroll
      for (int j = 0; j < 4; ++j) {
        const int row = rb + j;
        float v;
        if (EPI == 1) {
          v = __expf(acc[m][n][j] * alpha);
          rs[j] += v;
        } else if (EPI == 2) {
          v = acc[m][n][j] * rin[j];
        } else {
          v = acc[m][n][j] * alpha;
          if (BIAS_MODE == 1) v += bN;
          if (BIAS_MODE == 2) v += bias[row];
        }
        const long off = (long)bz * sCb + (long)row * ldc + col;
        if (OUT_BF16)
          ((bf16*)Cp)[off] = __float2bfloat16(v);
        else
          ((float*)Cp)[off] = v;
      }
    }
    if (EPI == 1) {
#pragma unroll
      for (int j = 0; j < 4; ++j) {
        float s = rs[j];
#pragma unroll
        for (int sh = 1; sh < 16; sh <<= 1) s += __shfl_xor(s, sh, 64);
        if (r15 == 0) atomicAdd(sc + (long)bz * scb + rb + j, s);
      }
    }
  }
}

// ---------- host ----------
extern "C" void kernel_launch(void* const* d_in, const int* in_sizes, int n_in,
                              void* d_out, int out_size, void* d_ws, size_t ws_size,
                              hipStream_t stream) {
  const float* input   = (const float*)d_in[0];   // [8,512,4096]
  const float* context = (const float*)d_in[1];   // [8,512,1024]
  const float* pin_w   = (const float*)d_in[2];
  const float* pin_b   = (const float*)d_in[3];
  const float* wq_w    = (const float*)d_in[4];
  const float* wq_b    = (const float*)d_in[5];
  const float* wk_w    = (const float*)d_in[6];
  const float* wk_b    = (const float*)d_in[7];
  const float* wv_w    = (const float*)d_in[8];
  const float* wv_b    = (const float*)d_in[9];
  const float* pout_w  = (const float*)d_in[10];
  const float* pout_b  = (const float*)d_in[11];

  char* ws = (char*)d_ws;
  size_t off = 0;
  auto alloc = [&](size_t bytes) -> void* {
    void* p = ws + off;
    off += (bytes + 255) & ~(size_t)255;
    return p;
  };
  bf16* poutw = (bf16*)alloc((size_t)512 * 1024 * 2);
  bf16* wqT  = (bf16*)alloc((size_t)512 * 512 * 2);
  bf16* wkT  = (bf16*)alloc((size_t)512 * 512 * 2);
  bf16* wvT  = (bf16*)alloc((size_t)512 * 512 * 2);
  bf16* pinT = (bf16*)alloc((size_t)512 * 512 * 2);
  bf16* WQc  = (bf16*)alloc((size_t)512 * 512 * 2);
  float* bQc = (float*)alloc((size_t)512 * 4);
  bf16* cat  = (bf16*)alloc((size_t)32768 * 1024 * 2);  // L=input^T, R=attn out
  bf16* ctxt = (bf16*)alloc((size_t)8192 * 512 * 2);
  bf16* Qb   = (bf16*)alloc((size_t)32768 * 512 * 2);
  bf16* Kmb  = (bf16*)alloc((size_t)8192 * 512 * 2);
  bf16* Vtb  = (bf16*)alloc((size_t)8 * 512 * 1024 * 2);
  bf16* Sb   = (bf16*)alloc((size_t)8 * 4096 * 1024 * 2);
  float* rsum = (float*)alloc((size_t)32768 * 4);

  dim3 blk(256);

  // allow 128 KiB dynamic LDS on the 256^2 instantiations (idempotent)
  hipFuncSetAttribute((const void*)gemm256_kernel<1, 1, 0>,
                      hipFuncAttributeMaxDynamicSharedMemorySize, 131072);
  hipFuncSetAttribute((const void*)gemm256_kernel<1, 0, 1>,
                      hipFuncAttributeMaxDynamicSharedMemorySize, 131072);
  hipFuncSetAttribute((const void*)gemm256_kernel<1, 0, 2>,
                      hipFuncAttributeMaxDynamicSharedMemorySize, 131072);
  hipFuncSetAttribute((const void*)gemm256_kernel<0, 2, 0>,
                      hipFuncAttributeMaxDynamicSharedMemorySize, 131072);

  // weight prep
  convert_f32_bf16<<<2048, blk, 0, stream>>>(pout_w, poutw, 512 * 1024);
  zero_f32<<<128, blk, 0, stream>>>(rsum, 32768);
  transpose_w4<<<dim3(16, 16, 4), blk, 0, stream>>>(wq_w, wk_w, wv_w, pin_w,
                                                    wqT, wkT, wvT, pinT);
  bias_combine<<<2, blk, 0, stream>>>(pin_b, wq_w, wq_b, bQc);
  // input -> cat left half
  transpose_f32_to_bf16<<<dim3(128, 16, 8), blk, 0, stream>>>(
      input, cat, 4096, (long)512 * 4096, (long)4096 * 1024, 1024, 0);
  // context -> ctxt
  transpose_f32_to_bf16<<<dim3(32, 16, 8), blk, 0, stream>>>(
      context, ctxt, 1024, (long)512 * 1024, (long)1024 * 512, 512, 0);

  const float scale = 0.04419417382415922f;  // 512^-0.5

  // WQc[o,c] = sum_e wq[e,o]*pin_w[e,c]  (128^2 kernel, grid 4x4)
  gemm_bt_kernel<1, 0, 0><<<dim3(16), blk, 0, stream>>>(
      wqT, 0, 512, pinT, 0, 512, WQc, 0, 512, nullptr, nullptr, 0, 1.f, 512, 2, 2);
  // K = ctxt @ wkT^T + wk_b  [8192,512]  (128^2, grid 4x64)
  gemm_bt_kernel<1, 1, 0><<<dim3(256), blk, 0, stream>>>(
      ctxt, 0, 512, wkT, 0, 512, Kmb, 0, 512, wk_b, nullptr, 0, 1.f, 512, 2, 6);
  // Vt_b = wvT @ ctx_b^T + wv_b  [8][512,1024]  (128^2, grid 8x4x8)
  gemm_bt_kernel<1, 2, 0><<<dim3(256), blk, 0, stream>>>(
      wvT, 0, 512, ctxt, (long)1024 * 512, 512, Vtb, (long)512 * 1024, 1024,
      wv_b, nullptr, 0, 1.f, 512, 3, 2);

  // Q = catL @ WQc^T + bQc   [32768,512]  (256^2, grid 2x128)
  gemm256_kernel<1, 1, 0><<<dim3(256), dim3(512), 131072, stream>>>(
      cat, 0, 1024, WQc, 0, 512, Qb, 0, 512, bQc, nullptr, 0, 1.f, 512, 1, 7);
  // expS_b = exp(scale*Q_b@K_b^T), rowsum->rsum  [8][4096,1024] (256^2, 4x16x8)
  gemm256_kernel<1, 0, 1><<<dim3(512), dim3(512), 131072, stream>>>(
      Qb, (long)4096 * 512, 512, Kmb, (long)1024 * 512, 512, Sb,
      (long)4096 * 1024, 1024, nullptr, rsum, 4096, scale, 512, 2, 4);
  // O_b = (expS_b @ Vt_b^T) / rsum -> cat right half  (256^2, 2x16x8)
  gemm256_kernel<1, 0, 2><<<dim3(256), dim3(512), 131072, stream>>>(
      Sb, (long)4096 * 1024, 1024, Vtb, (long)512 * 1024, 1024,
      (void*)(cat + 512), (long)4096 * 1024, 1024, nullptr, rsum, 4096, 1.f,
      1024, 1, 4);
  // out_b^T = poutw @ cat_b^T + pout_b -> d_out [8][512][4096] fp32 (256^2, 16x2x8)
  gemm256_kernel<0, 2, 0><<<dim3(256), dim3(512), 131072, stream>>>(
      poutw, 0, 1024, cat, (long)4096 * 1024, 1024, d_out,
      (long)512 * 4096, 4096, pout_b, nullptr, 0, 1.f, 1024, 4, 1);
}